// Round 5
// baseline (185.628 us; speedup 1.0000x reference)
//
#include <hip/hip_runtime.h>
#include <stdint.h>

// R5: still no bench data (5 infra failures; none attributable to our code —
// the one container death ran the barrier-free R1 kernel). Keeping R4's
// fused structure; two defensive changes only:
//  1. BOUNDED spin barrier (~2e7 iters): a co-residency violation now yields
//     a detectably-wrong answer instead of a hang/dead container.
//  2. Barrier ordering: __syncthreads() (drains all threads' bound-atomics
//     via vmcnt before s_barrier) BEFORE t0's device fence + release-add.
// Structure: convert fp32->bf16 once; 528 upper-triangular 128x128 sim tiles
// (sim symmetric -> dual epilogue on off-diagonal tiles); ONE GEMM per tile:
// bounds epilogue -> device-wide barrier (co-residency: __launch_bounds__
// (256,3) => 3 blocks/CU * 256 CU = 768 >= 528, verified via host occupancy
// query, else two-pass fallback) -> stats epilogue on retained registers.
// Numerics: bf16 hi*hi sim (loss err ~1e-6; pos side cancels over ~41-term
// sums, neg side is ~1e-7 of loss, masks self-consistent with bounds);
// unshifted logsumexp: softplus(log S) = log1p(S), |w|<=60 so no overflow.

#define BS 4096
#define DIM 512
#define NTILES 528

typedef __attribute__((ext_vector_type(8))) short short8;
typedef __attribute__((ext_vector_type(4))) float f32x4;

#define TILE_USH (128 * 64)   // ushorts per LDS operand tile (16 KB)

// ---- helpers -------------------------------------------------------------
__device__ __forceinline__ unsigned fenc(float f){           // order-preserving float->uint
  unsigned u = __float_as_uint(f);
  return (u & 0x80000000u) ? ~u : (u | 0x80000000u);
}
__device__ __forceinline__ float fdec(unsigned e){
  unsigned u = (e & 0x80000000u) ? (e & 0x7fffffffu) : ~e;
  return __uint_as_float(u);
}
__device__ __forceinline__ ushort f2bf(float f){             // RNE fp32->bf16
  unsigned u = __float_as_uint(f);
  return (ushort)((u + 0x7fffu + ((u >> 16) & 1u)) >> 16);
}
__device__ __forceinline__ void gld_lds16(void* ldsp, const void* gp){
  __builtin_amdgcn_global_load_lds((const __attribute__((address_space(1))) void*)gp,
                                   (__attribute__((address_space(3))) void*)ldsp, 16, 0, 0);
}

// ---- K0: fp32 -> bf16 ----------------------------------------------------
__global__ void k_convert(const float* __restrict__ x, ushort* __restrict__ xh){
  int i = blockIdx.x * blockDim.x + threadIdx.x;   // over BS*DIM/4
  float4 v = ((const float4*)x)[i];
  ((ushort4*)xh)[i] = make_ushort4(f2bf(v.x), f2bf(v.y), f2bf(v.z), f2bf(v.w));
}

// ---- GEMM core: one 128x128 sim tile into acc ----------------------------
// m97-verified pattern: both operands row-major from Xh (sim = Xh * Xh^T),
// global_load_lds w=16 with XOR-pre-swizzled GLOBAL source + linear LDS dest
// (rule #21), read side applies the same involution -> ~2-way conflicts max.
__device__ __forceinline__ void gemm_tile(f32x4 (&acc)[4][4], ushort* lds,
                                          const ushort* __restrict__ Xh,
                                          int Rm, int Rn, int t)
{
  const int l  = t & 63;
  const int w  = t >> 6;
  const int wm = w >> 1, wn = w & 1;
  const int lc = l & 15;
  const int lq = l >> 4;
  const int r0 = t >> 3;                      // staged row 0..31 (per rep)
  const int gx = (t & 7) ^ (r0 & 7);          // swizzled source col-group
  const int lds_i = t * 8;                    // linear 16B slot (wave-uniform+lane*16)

  #pragma unroll
  for (int i = 0; i < 4; ++i)
    #pragma unroll
    for (int j = 0; j < 4; ++j) acc[i][j] = (f32x4){0.f, 0.f, 0.f, 0.f};

  for (int ks = 0; ks < 8; ++ks){
    const int kb = ks * 64 + gx * 8;
    #pragma unroll
    for (int rep = 0; rep < 4; ++rep){
      const int row = rep * 32 + r0;
      const int lo  = rep * 2048 + lds_i;
      gld_lds16(&lds[lo],            Xh + (size_t)(Rm + row) * DIM + kb);
      gld_lds16(&lds[TILE_USH + lo], Xh + (size_t)(Rn + row) * DIM + kb);
    }
    __syncthreads();   // compiler drains vmcnt before s_barrier
    #pragma unroll
    for (int kk = 0; kk < 2; ++kk){
      const int gr = kk * 4 + lq;
      const int sl = (gr ^ (l & 7)) * 8;      // frag row & 7 == l & 7 (row bases are mult of 16)
      short8 ah[4], bh[4];
      #pragma unroll
      for (int f = 0; f < 4; ++f){
        ah[f] = *(const short8*)&lds[(wm * 64 + f * 16 + lc) * 64 + sl];
        bh[f] = *(const short8*)&lds[TILE_USH + (wn * 64 + f * 16 + lc) * 64 + sl];
      }
      #pragma unroll
      for (int fm = 0; fm < 4; ++fm)
        #pragma unroll
        for (int fn = 0; fn < 4; ++fn)
          acc[fm][fn] = __builtin_amdgcn_mfma_f32_16x16x32_bf16(ah[fm], bh[fn], acc[fm][fn], 0, 0, 0);
    }
    __syncthreads();
  }
}

// ---- epilogue 1: per-row bounds (standard + transposed) ------------------
__device__ __forceinline__ void epi_bounds(const f32x4 (&acc)[4][4],
    const int* __restrict__ labels, const int (&labr)[4][4],
    unsigned* pos_enc, unsigned* neg_enc,
    int Rm, int Rn, bool diag, int t)
{
  const int l  = t & 63;
  const int w  = t >> 6;
  const int wm = w >> 1, wn = w & 1;
  const int lc = l & 15, lq = l >> 4;
  const int crow0 = Rm + wm * 64;
  const int ccol0 = Rn + wn * 64;
  const float INF = __builtin_inff();

  // standard: bounds for rows in Rm-block (reduce over this tile's columns)
  #pragma unroll
  for (int fm = 0; fm < 4; ++fm){
    float mn[4] = {INF, INF, INF, INF};
    float mx[4] = {-INF, -INF, -INF, -INF};
    #pragma unroll
    for (int fn = 0; fn < 4; ++fn){
      const int gc = ccol0 + fn * 16 + lc;
      const int labc = labels[gc];
      #pragma unroll
      for (int v = 0; v < 4; ++v){
        const float s = acc[fm][fn][v];
        const int grow = crow0 + fm * 16 + lq * 4 + v;
        const bool same = (labc == labr[fm][v]);
        mn[v] = fminf(mn[v], (same && (grow != gc)) ? s : INF);
        mx[v] = fmaxf(mx[v], same ? -INF : s);
      }
    }
    #pragma unroll
    for (int off = 1; off < 16; off <<= 1)
      #pragma unroll
      for (int v = 0; v < 4; ++v){
        mn[v] = fminf(mn[v], __shfl_xor(mn[v], off));
        mx[v] = fmaxf(mx[v], __shfl_xor(mx[v], off));
      }
    if (lc == 0){
      #pragma unroll
      for (int v = 0; v < 4; ++v){
        const int grow = crow0 + fm * 16 + lq * 4 + v;
        if (mn[v] < INF)  atomicMin(&pos_enc[grow], fenc(mn[v]));
        if (mx[v] > -INF) atomicMax(&neg_enc[grow], fenc(mx[v]));
      }
    }
  }
  if (!diag){
    // transposed: bounds for rows == this tile's column indices
    #pragma unroll
    for (int fn = 0; fn < 4; ++fn){
      const int gc = ccol0 + fn * 16 + lc;
      const int labc = labels[gc];
      float mn = INF, mx = -INF;
      #pragma unroll
      for (int fm = 0; fm < 4; ++fm)
        #pragma unroll
        for (int v = 0; v < 4; ++v){
          const float s = acc[fm][fn][v];
          const bool same = (labc == labr[fm][v]);
          mn = fminf(mn, same ? s : INF);        // grow != gc off-diagonal
          mx = fmaxf(mx, same ? -INF : s);
        }
      #pragma unroll
      for (int off = 16; off < 64; off <<= 1){
        mn = fminf(mn, __shfl_xor(mn, off));
        mx = fmaxf(mx, __shfl_xor(mx, off));
      }
      if (l < 16){
        if (mn < INF)  atomicMin(&pos_enc[gc], fenc(mn));
        if (mx > -INF) atomicMax(&neg_enc[gc], fenc(mx));
      }
    }
  }
}

// ---- bound readers (AB=true: agent-scope atomic load, for fused path) ----
template<bool AB>
__device__ __forceinline__ unsigned rd_enc(unsigned* p){
  if (AB) return __hip_atomic_load(p, __ATOMIC_RELAXED, __HIP_MEMORY_SCOPE_AGENT);
  return *p;
}

// ---- epilogue 2: per-column masked stats (standard + transposed) ---------
template<bool AB>
__device__ __forceinline__ void epi_stats(const f32x4 (&acc)[4][4],
    const int* __restrict__ labels, const int (&labr)[4][4],
    unsigned* pos_enc, unsigned* neg_enc,
    unsigned* maxN_enc, unsigned* minN_enc, float* SN,
    unsigned* maxP_enc, unsigned* minP_enc, float* SP,
    int Rm, int Rn, bool diag, int t)
{
  const int l  = t & 63;
  const int w  = t >> 6;
  const int wm = w >> 1, wn = w & 1;
  const int lc = l & 15, lq = l >> 4;
  const int crow0 = Rm + wm * 64;
  const int ccol0 = Rn + wn * 64;
  const float INF = __builtin_inff();

  // standard: stats for columns in Rn-block (reduce over tile rows)
  #pragma unroll
  for (int fn = 0; fn < 4; ++fn){
    const int gc = ccol0 + fn * 16 + lc;
    const int labc = labels[gc];
    const unsigned pe = rd_enc<AB>(&pos_enc[gc]);
    const float pb = (pe == 0xFFFFFFFFu) ? INF : fdec(pe);    // empty -> +inf
    const unsigned ne = rd_enc<AB>(&neg_enc[gc]);
    const float nb = (ne == 0u) ? -INF : fdec(ne);            // empty -> -inf
    float mxN = -INF, mnN = INF, sN = 0.f;
    float mxP = -INF, mnP = INF, sP = 0.f;
    #pragma unroll
    for (int fm = 0; fm < 4; ++fm)
      #pragma unroll
      for (int v = 0; v < 4; ++v){
        const float s = acc[fm][fn][v];
        const bool same = (labc == labr[fm][v]);
        const float wN = 40.0f * (s - 0.5f);
        const bool mN = (!same) && (s + 0.1f > pb);
        const float mvN = mN ? wN : 0.0f;                     // zeros included: ref's m = sims*mask
        mxN = fmaxf(mxN, mvN); mnN = fminf(mnN, mvN);
        sN += mN ? __expf(wN) : 0.0f;
        const float wP = -2.0f * (s - 0.5f);
        const bool mP = same && (s - 0.1f < nb);              // diagonal included, as in ref
        const float mvP = mP ? wP : 0.0f;
        mxP = fmaxf(mxP, mvP); mnP = fminf(mnP, mvP);
        sP += mP ? __expf(wP) : 0.0f;
      }
    #pragma unroll
    for (int off = 16; off < 64; off <<= 1){
      mxN = fmaxf(mxN, __shfl_xor(mxN, off));
      mnN = fminf(mnN, __shfl_xor(mnN, off));
      sN += __shfl_xor(sN, off);
      mxP = fmaxf(mxP, __shfl_xor(mxP, off));
      mnP = fminf(mnP, __shfl_xor(mnP, off));
      sP += __shfl_xor(sP, off);
    }
    if (l < 16){
      atomicMax(&maxN_enc[gc], fenc(mxN));
      atomicMin(&minN_enc[gc], fenc(mnN));
      atomicAdd(&SN[gc], sN);
      atomicMax(&maxP_enc[gc], fenc(mxP));
      atomicMin(&minP_enc[gc], fenc(mnP));
      atomicAdd(&SP[gc], sP);
    }
  }
  if (!diag){
    // transposed: stats for columns == this tile's row indices
    #pragma unroll
    for (int fm = 0; fm < 4; ++fm){
      float pbr[4], nbr[4];
      #pragma unroll
      for (int v = 0; v < 4; ++v){
        const int grow = crow0 + fm * 16 + lq * 4 + v;
        const unsigned pe = rd_enc<AB>(&pos_enc[grow]);
        pbr[v] = (pe == 0xFFFFFFFFu) ? INF : fdec(pe);
        const unsigned ne = rd_enc<AB>(&neg_enc[grow]);
        nbr[v] = (ne == 0u) ? -INF : fdec(ne);
      }
      float mxN[4], mnN[4], sN[4], mxP[4], mnP[4], sP[4];
      #pragma unroll
      for (int v = 0; v < 4; ++v){
        mxN[v] = -INF; mnN[v] = INF; sN[v] = 0.f;
        mxP[v] = -INF; mnP[v] = INF; sP[v] = 0.f;
      }
      #pragma unroll
      for (int fn = 0; fn < 4; ++fn){
        const int gc = ccol0 + fn * 16 + lc;
        const int labc = labels[gc];
        #pragma unroll
        for (int v = 0; v < 4; ++v){
          const float s = acc[fm][fn][v];
          const bool same = (labc == labr[fm][v]);
          const float wN = 40.0f * (s - 0.5f);
          const bool mN = (!same) && (s + 0.1f > pbr[v]);
          const float mvN = mN ? wN : 0.0f;
          mxN[v] = fmaxf(mxN[v], mvN); mnN[v] = fminf(mnN[v], mvN);
          sN[v] += mN ? __expf(wN) : 0.0f;
          const float wP = -2.0f * (s - 0.5f);
          const bool mP = same && (s - 0.1f < nbr[v]);
          const float mvP = mP ? wP : 0.0f;
          mxP[v] = fmaxf(mxP[v], mvP); mnP[v] = fminf(mnP[v], mvP);
          sP[v] += mP ? __expf(wP) : 0.0f;
        }
      }
      #pragma unroll
      for (int off = 1; off < 16; off <<= 1)
        #pragma unroll
        for (int v = 0; v < 4; ++v){
          mxN[v] = fmaxf(mxN[v], __shfl_xor(mxN[v], off));
          mnN[v] = fminf(mnN[v], __shfl_xor(mnN[v], off));
          sN[v] += __shfl_xor(sN[v], off);
          mxP[v] = fmaxf(mxP[v], __shfl_xor(mxP[v], off));
          mnP[v] = fminf(mnP[v], __shfl_xor(mnP[v], off));
          sP[v] += __shfl_xor(sP[v], off);
        }
      if (lc == 0){
        #pragma unroll
        for (int v = 0; v < 4; ++v){
          const int grow = crow0 + fm * 16 + lq * 4 + v;
          atomicMax(&maxN_enc[grow], fenc(mxN[v]));
          atomicMin(&minN_enc[grow], fenc(mnN[v]));
          atomicAdd(&SN[grow], sN[v]);
          atomicMax(&maxP_enc[grow], fenc(mxP[v]));
          atomicMin(&minP_enc[grow], fenc(mnP[v]));
          atomicAdd(&SP[grow], sP[v]);
        }
      }
    }
  }
}

// ---- tile decode: 528 upper-tri tiles, XCD-swizzled (528 = 8*66) ---------
__device__ __forceinline__ void decode_tile(int bid, int& Rm, int& Rn, bool& diag){
  int wg = (bid & 7) * 66 + (bid >> 3);
  int ii = wg, bm = 0;
  while (ii >= 32 - bm){ ii -= 32 - bm; ++bm; }
  const int bn = bm + ii;
  diag = (bm == bn);
  Rm = bm * 128; Rn = bn * 128;
}

// ---- FUSED kernel: GEMM once -> bounds -> grid barrier -> stats ----------
__global__ __launch_bounds__(256, 3)
void k_fused(const ushort* __restrict__ Xh, const int* __restrict__ labels,
             unsigned* pos_enc, unsigned* neg_enc,
             unsigned* maxN_enc, unsigned* minN_enc, float* SN,
             unsigned* maxP_enc, unsigned* minP_enc, float* SP,
             unsigned* bar)
{
  __shared__ ushort lds[2 * TILE_USH];
  const int t = threadIdx.x;
  int Rm, Rn; bool diag;
  decode_tile((int)blockIdx.x, Rm, Rn, diag);

  f32x4 acc[4][4];
  gemm_tile(acc, lds, Xh, Rm, Rn, t);

  const int wm = (t >> 6) >> 1, lq = (t & 63) >> 4;
  int labr[4][4];
  #pragma unroll
  for (int fm = 0; fm < 4; ++fm)
    #pragma unroll
    for (int v = 0; v < 4; ++v)
      labr[fm][v] = labels[Rm + wm * 64 + fm * 16 + lq * 4 + v];

  epi_bounds(acc, labels, labr, pos_enc, neg_enc, Rm, Rn, diag, t);

  // ---- device-wide barrier. Co-residency: 3 blocks/CU * 256 CU = 768 >=
  // 528, validated host-side before choosing this kernel. __syncthreads
  // first: the compiler's waitcnt drain guarantees every thread's bound-
  // atomics completed at the coherent point before t0 releases. Spin is
  // BOUNDED: a violation produces a detectably-wrong answer, not a hang.
  __syncthreads();
  if (t == 0){
    __threadfence();
    __hip_atomic_fetch_add(bar, 1u, __ATOMIC_ACQ_REL, __HIP_MEMORY_SCOPE_AGENT);
    unsigned spins = 0;
    while (__hip_atomic_load(bar, __ATOMIC_ACQUIRE, __HIP_MEMORY_SCOPE_AGENT) < (unsigned)NTILES
           && ++spins < 20000000u)
      __builtin_amdgcn_s_sleep(8);
  }
  __syncthreads();

  epi_stats<true>(acc, labels, labr, pos_enc, neg_enc,
                  maxN_enc, minN_enc, SN, maxP_enc, minP_enc, SP, Rm, Rn, diag, t);
}

// ---- fallback: two-pass kernels (R3 structure) ---------------------------
template<int PHASE>
__global__ __launch_bounds__(256)
void k_gemm(const ushort* __restrict__ Xh, const int* __restrict__ labels,
            unsigned* pos_enc, unsigned* neg_enc,
            unsigned* maxN_enc, unsigned* minN_enc, float* SN,
            unsigned* maxP_enc, unsigned* minP_enc, float* SP)
{
  __shared__ ushort lds[2 * TILE_USH];
  const int t = threadIdx.x;
  int Rm, Rn; bool diag;
  decode_tile((int)blockIdx.x, Rm, Rn, diag);

  f32x4 acc[4][4];
  gemm_tile(acc, lds, Xh, Rm, Rn, t);

  const int wm = (t >> 6) >> 1, lq = (t & 63) >> 4;
  int labr[4][4];
  #pragma unroll
  for (int fm = 0; fm < 4; ++fm)
    #pragma unroll
    for (int v = 0; v < 4; ++v)
      labr[fm][v] = labels[Rm + wm * 64 + fm * 16 + lq * 4 + v];

  if (PHASE == 1)
    epi_bounds(acc, labels, labr, pos_enc, neg_enc, Rm, Rn, diag, t);
  else
    epi_stats<false>(acc, labels, labr, pos_enc, neg_enc,
                     maxN_enc, minN_enc, SN, maxP_enc, minP_enc, SP, Rm, Rn, diag, t);
}

// ---- K3: per-column finalize + scalar loss (single block) ----------------
__global__ void k_finalize(const unsigned* __restrict__ maxN_enc, const unsigned* __restrict__ minN_enc,
                           const float* __restrict__ SN,
                           const unsigned* __restrict__ maxP_enc, const unsigned* __restrict__ minP_enc,
                           const float* __restrict__ SP, float* __restrict__ out)
{
  const int t = threadIdx.x;                  // 0..1023
  float sumP = 0.f, cP = 0.f, sumN = 0.f, cN = 0.f;
  #pragma unroll
  for (int i = 0; i < 4; ++i){
    const int c = t + i * 1024;
    const float mxN = fdec(maxN_enc[c]), mnN = fdec(minN_enc[c]);
    if (mxN + mnN != 0.0f){ sumN += log1pf(SN[c]); cN += 1.0f; }   // softplus(log S)=log1p(S)
    const float mxP = fdec(maxP_enc[c]), mnP = fdec(minP_enc[c]);
    if (mxP + mnP != 0.0f){ sumP += log1pf(SP[c]); cP += 1.0f; }
  }
  #pragma unroll
  for (int off = 32; off; off >>= 1){
    sumP += __shfl_down(sumP, off); cP += __shfl_down(cP, off);
    sumN += __shfl_down(sumN, off); cN += __shfl_down(cN, off);
  }
  __shared__ float red[16][4];
  const int w = t >> 6;
  if ((t & 63) == 0){ red[w][0] = sumP; red[w][1] = cP; red[w][2] = sumN; red[w][3] = cN; }
  __syncthreads();
  if (t == 0){
    float SPs = 0.f, CPs = 0.f, SNs = 0.f, CNs = 0.f;
    for (int i = 0; i < 16; ++i){ SPs += red[i][0]; CPs += red[i][1]; SNs += red[i][2]; CNs += red[i][3]; }
    const float LN2 = 0.69314718055994531f;   // softplus(0)
    const float tP = (CPs > 0.f) ? (SPs / 2.0f)  / fmaxf(CPs, 1.f) : LN2 / 2.0f;
    const float tN = (CNs > 0.f) ? (SNs / 40.0f) / fmaxf(CNs, 1.f) : LN2 / 40.0f;
    out[0] = tP + tN;
  }
}

// ---- launch --------------------------------------------------------------
extern "C" void kernel_launch(void* const* d_in, const int* in_sizes, int n_in,
                              void* d_out, int out_size, void* d_ws, size_t ws_size,
                              hipStream_t stream) {
  const float* x    = (const float*)d_in[0];   // batch (4096x512 fp32)
  const int* labels = (const int*)d_in[1];     // int32 labels
  char* W = (char*)d_ws;
  // ws: Xh 4MB | Z(memset0): neg,maxN,maxP,SN,SP,bar (6x16KB) | F(memsetFF): pos,minN,minP (3x16KB)
  ushort* Xh = (ushort*)W;
  char* Z = W + (4u << 20);
  unsigned* neg_enc  = (unsigned*)(Z + 0 * 16384);
  unsigned* maxN_enc = (unsigned*)(Z + 1 * 16384);
  unsigned* maxP_enc = (unsigned*)(Z + 2 * 16384);
  float*    SN       = (float*)   (Z + 3 * 16384);
  float*    SP       = (float*)   (Z + 4 * 16384);
  unsigned* bar      = (unsigned*)(Z + 5 * 16384);
  char* F = Z + 6 * 16384;
  unsigned* pos_enc  = (unsigned*)(F + 0 * 16384);
  unsigned* minN_enc = (unsigned*)(F + 1 * 16384);
  unsigned* minP_enc = (unsigned*)(F + 2 * 16384);

  hipMemsetAsync(Z, 0x00, 6 * 16384, stream);
  hipMemsetAsync(F, 0xFF, 3 * 16384, stream);
  k_convert<<<(BS * DIM / 4) / 256, 256, 0, stream>>>(x, Xh);

  // choose fused (needs all 528 blocks co-resident) or two-pass fallback;
  // pure host-side queries -> deterministic, graph-capture-safe
  int nb = 0, ncu = 0;
  hipDeviceProp_t prop;
  int dev = 0;
  hipGetDevice(&dev);
  if (hipGetDeviceProperties(&prop, dev) == hipSuccess) ncu = prop.multiProcessorCount;
  bool fused = (hipOccupancyMaxActiveBlocksPerMultiprocessor(&nb, k_fused, 256, 0) == hipSuccess)
               && (ncu > 0) && ((long)nb * ncu >= NTILES);

  if (fused){
    k_fused<<<NTILES, 256, 0, stream>>>(Xh, labels, pos_enc, neg_enc,
                                        maxN_enc, minN_enc, SN, maxP_enc, minP_enc, SP, bar);
  } else {
    k_gemm<1><<<NTILES, 256, 0, stream>>>(Xh, labels, pos_enc, neg_enc,
                                          maxN_enc, minN_enc, SN, maxP_enc, minP_enc, SP);
    k_gemm<2><<<NTILES, 256, 0, stream>>>(Xh, labels, pos_enc, neg_enc,
                                          maxN_enc, minN_enc, SN, maxP_enc, minP_enc, SP);
  }
  k_finalize<<<1, 1024, 0, stream>>>(maxN_enc, minN_enc, SN, maxP_enc, minP_enc, SP, (float*)d_out);
}

// Round 9
// 179.447 us; speedup vs baseline: 1.0344x; 1.0344x over previous
//
#include <hip/hip_runtime.h>
#include <stdint.h>

// R9 == R6 resubmitted (R6/R7/R8 never ran: GPUAcquisitionTimeout x3).
// Basis: R5 bench 185.6us, absmax 0.0, MfmaUtil 1.7%, WRITE_SIZE 164.9MB ->
// ~2.2M device-scope atomics (64B coherent-point RMW each) + barrier spin
// dominated ~90% of runtime. Fix: ZERO global atomics. Triangular
// decomposition gives every (slot,index) a unique writer block ->
// write-once partial arrays:
//   k_bounds: GEMM + per-row bound partials posB/negB[32][4096] (plain stores)
//   k_redbounds: 32->1 min/max -> pos_bound/neg_bound[4096]
//   k_stats: GEMM + per-col sum-exp partials SN/SP[32][4096]
//   k_finalize: reduce 32 slots/col + loss
// Kernel boundaries replace the grid barrier (free device-wide coherence; no
// co-residency constraint/spin). Extra GEMM pass costs only ~3.4us (measured
// via MfmaUtil). nz quirk via S != 0 (exact for empty cols; differs only on
// measure-zero exact cancellation; exp(-60)~9e-27 can't underflow fp32).
// Cross-wave epilogue combines via 4KB LDS scratch (GEMM buffer, dead after
// K-loop). No memsets (all ws written-before-read; slot coverage proven
// exhaustive). GEMM core unchanged from R5-validated (128x128 tile, BK=64,
// 16x16x32 bf16 MFMA, global_load_lds w=16, XOR-pre-swizzled source+read).

#define BS 4096
#define DIM 512
#define NTILES 528
#define NSLOT 32

typedef __attribute__((ext_vector_type(8))) short short8;
typedef __attribute__((ext_vector_type(4))) float f32x4;

#define TILE_USH (128 * 64)   // ushorts per LDS operand tile (16 KB)

// ---- helpers -------------------------------------------------------------
__device__ __forceinline__ ushort f2bf(float f){             // RNE fp32->bf16
  unsigned u = __float_as_uint(f);
  return (ushort)((u + 0x7fffu + ((u >> 16) & 1u)) >> 16);
}
__device__ __forceinline__ void gld_lds16(void* ldsp, const void* gp){
  __builtin_amdgcn_global_load_lds((const __attribute__((address_space(1))) void*)gp,
                                   (__attribute__((address_space(3))) void*)ldsp, 16, 0, 0);
}

// ---- K0: fp32 -> bf16 ----------------------------------------------------
__global__ void k_convert(const float* __restrict__ x, ushort* __restrict__ xh){
  int i = blockIdx.x * blockDim.x + threadIdx.x;   // over BS*DIM/4
  float4 v = ((const float4*)x)[i];
  ((ushort4*)xh)[i] = make_ushort4(f2bf(v.x), f2bf(v.y), f2bf(v.z), f2bf(v.w));
}

// ---- tile decode: 528 upper-tri tiles, XCD-swizzled (528 = 8*66) ---------
__device__ __forceinline__ void decode_tile(int bid, int& Rm, int& Rn, bool& diag){
  int wg = (bid & 7) * 66 + (bid >> 3);
  int ii = wg, bm = 0;
  while (ii >= 32 - bm){ ii -= 32 - bm; ++bm; }
  const int bn = bm + ii;
  diag = (bm == bn);
  Rm = bm * 128; Rn = bn * 128;
}

// ---- GEMM core: one 128x128 sim tile into acc (validated R5) -------------
__device__ __forceinline__ void gemm_tile(f32x4 (&acc)[4][4], ushort* lds,
                                          const ushort* __restrict__ Xh,
                                          int Rm, int Rn, int t)
{
  const int l  = t & 63;
  const int w  = t >> 6;
  const int wm = w >> 1, wn = w & 1;
  const int lc = l & 15;
  const int lq = l >> 4;
  const int r0 = t >> 3;
  const int gx = (t & 7) ^ (r0 & 7);          // swizzled source col-group
  const int lds_i = t * 8;

  #pragma unroll
  for (int i = 0; i < 4; ++i)
    #pragma unroll
    for (int j = 0; j < 4; ++j) acc[i][j] = (f32x4){0.f, 0.f, 0.f, 0.f};

  for (int ks = 0; ks < 8; ++ks){
    const int kb = ks * 64 + gx * 8;
    #pragma unroll
    for (int rep = 0; rep < 4; ++rep){
      const int row = rep * 32 + r0;
      const int lo  = rep * 2048 + lds_i;
      gld_lds16(&lds[lo],            Xh + (size_t)(Rm + row) * DIM + kb);
      gld_lds16(&lds[TILE_USH + lo], Xh + (size_t)(Rn + row) * DIM + kb);
    }
    __syncthreads();
    #pragma unroll
    for (int kk = 0; kk < 2; ++kk){
      const int gr = kk * 4 + lq;
      const int sl = (gr ^ (l & 7)) * 8;
      short8 ah[4], bh[4];
      #pragma unroll
      for (int f = 0; f < 4; ++f){
        ah[f] = *(const short8*)&lds[(wm * 64 + f * 16 + lc) * 64 + sl];
        bh[f] = *(const short8*)&lds[TILE_USH + (wn * 64 + f * 16 + lc) * 64 + sl];
      }
      #pragma unroll
      for (int fm = 0; fm < 4; ++fm)
        #pragma unroll
        for (int fn = 0; fn < 4; ++fn)
          acc[fm][fn] = __builtin_amdgcn_mfma_f32_16x16x32_bf16(ah[fm], bh[fn], acc[fm][fn], 0, 0, 0);
    }
    __syncthreads();
  }
}

// ---- K1: GEMM + per-row bound PARTIALS -----------------------------------
// posB/negB are float[NSLOT][BS]; for row-tile r: slot s>=r written by std of
// tile (r,s) (diag included); slot s<r by transposed of tile (s,r). Once each.
__global__ __launch_bounds__(256)
void k_bounds(const ushort* __restrict__ Xh, const int* __restrict__ labels,
              float* __restrict__ posB, float* __restrict__ negB)
{
  __shared__ ushort lds[2 * TILE_USH];
  const int t = threadIdx.x;
  int Rm, Rn; bool diag;
  decode_tile((int)blockIdx.x, Rm, Rn, diag);
  const int bm = Rm >> 7, bn = Rn >> 7;

  f32x4 acc[4][4];
  gemm_tile(acc, lds, Xh, Rm, Rn, t);

  const int l  = t & 63;
  const int w  = t >> 6;
  const int wm = w >> 1, wn = w & 1;
  const int lc = l & 15, lq = l >> 4;
  const float INF = __builtin_inff();

  int labr[4][4];
  #pragma unroll
  for (int fm = 0; fm < 4; ++fm)
    #pragma unroll
    for (int v = 0; v < 4; ++v)
      labr[fm][v] = labels[Rm + wm * 64 + fm * 16 + lq * 4 + v];

  // LDS scratch (GEMM buffer dead after K-loop): 4 x 256 floats
  float* sMnS = (float*)lds;          // [wm][wn][r64] std per-row min
  float* sMxS = sMnS + 256;           // [wm][wn][r64] std per-row max
  float* sMnT = sMnS + 512;           // [wn][wm][c64] transposed per-col min
  float* sMxT = sMnS + 768;           // [wn][wm][c64] transposed per-col max

  // std: bounds for rows of Rm-block over this wave's 64 cols
  #pragma unroll
  for (int fm = 0; fm < 4; ++fm){
    float mn[4] = {INF, INF, INF, INF};
    float mx[4] = {-INF, -INF, -INF, -INF};
    #pragma unroll
    for (int fn = 0; fn < 4; ++fn){
      const int gc = Rn + wn * 64 + fn * 16 + lc;
      const int labc = labels[gc];
      #pragma unroll
      for (int v = 0; v < 4; ++v){
        const float s = acc[fm][fn][v];
        const int grow = Rm + wm * 64 + fm * 16 + lq * 4 + v;
        const bool same = (labc == labr[fm][v]);
        mn[v] = fminf(mn[v], (same && (grow != gc)) ? s : INF);
        mx[v] = fmaxf(mx[v], same ? -INF : s);
      }
    }
    #pragma unroll
    for (int off = 1; off < 16; off <<= 1)
      #pragma unroll
      for (int v = 0; v < 4; ++v){
        mn[v] = fminf(mn[v], __shfl_xor(mn[v], off));
        mx[v] = fmaxf(mx[v], __shfl_xor(mx[v], off));
      }
    if (lc == 0){
      #pragma unroll
      for (int v = 0; v < 4; ++v){
        const int r64 = fm * 16 + lq * 4 + v;
        sMnS[(wm * 2 + wn) * 64 + r64] = mn[v];
        sMxS[(wm * 2 + wn) * 64 + r64] = mx[v];
      }
    }
  }
  // transposed: bounds for rows == this tile's column indices (off-diag only)
  if (!diag){
    #pragma unroll
    for (int fn = 0; fn < 4; ++fn){
      const int gc = Rn + wn * 64 + fn * 16 + lc;
      const int labc = labels[gc];
      float mn = INF, mx = -INF;
      #pragma unroll
      for (int fm = 0; fm < 4; ++fm)
        #pragma unroll
        for (int v = 0; v < 4; ++v){
          const float s = acc[fm][fn][v];
          const bool same = (labc == labr[fm][v]);
          mn = fminf(mn, same ? s : INF);        // grow != gc off-diagonal
          mx = fmaxf(mx, same ? -INF : s);
        }
      #pragma unroll
      for (int off = 16; off < 64; off <<= 1){
        mn = fminf(mn, __shfl_xor(mn, off));
        mx = fmaxf(mx, __shfl_xor(mx, off));
      }
      if (l < 16){
        const int c64 = fn * 16 + lc;
        sMnT[(wn * 2 + wm) * 64 + c64] = mn;
        sMxT[(wn * 2 + wm) * 64 + c64] = mx;
      }
    }
  }
  __syncthreads();
  if (t < 128){
    const int h = t >> 6, r = t & 63;
    posB[(size_t)bn * BS + Rm + t] = fminf(sMnS[(h * 2 + 0) * 64 + r], sMnS[(h * 2 + 1) * 64 + r]);
    negB[(size_t)bn * BS + Rm + t] = fmaxf(sMxS[(h * 2 + 0) * 64 + r], sMxS[(h * 2 + 1) * 64 + r]);
    if (!diag){
      posB[(size_t)bm * BS + Rn + t] = fminf(sMnT[(h * 2 + 0) * 64 + r], sMnT[(h * 2 + 1) * 64 + r]);
      negB[(size_t)bm * BS + Rn + t] = fmaxf(sMxT[(h * 2 + 0) * 64 + r], sMxT[(h * 2 + 1) * 64 + r]);
    }
  }
}

// ---- K2: reduce bound partials 32 -> 1 -----------------------------------
__global__ void k_redbounds(const float* __restrict__ posB, const float* __restrict__ negB,
                            float* __restrict__ pos_bound, float* __restrict__ neg_bound){
  const int r = blockIdx.x * 256 + threadIdx.x;   // 16 blocks x 256
  float mn = __builtin_inff(), mx = -__builtin_inff();
  #pragma unroll
  for (int s = 0; s < NSLOT; ++s){
    mn = fminf(mn, posB[(size_t)s * BS + r]);
    mx = fmaxf(mx, negB[(size_t)s * BS + r]);
  }
  pos_bound[r] = mn;            // empty class -> +inf (masks all-false, as ref)
  neg_bound[r] = mx;            // empty -> -inf
}

// ---- K3: GEMM + per-col sum-exp PARTIALS ---------------------------------
// SNp/SPp float[NSLOT][BS]; for col-tile c: slot s<=c written by std of tile
// (s,c) (diag included); slot s>c by transposed of tile (c,s). Once each.
__global__ __launch_bounds__(256)
void k_stats(const ushort* __restrict__ Xh, const int* __restrict__ labels,
             const float* __restrict__ pos_bound, const float* __restrict__ neg_bound,
             float* __restrict__ SNp, float* __restrict__ SPp)
{
  __shared__ ushort lds[2 * TILE_USH];
  const int t = threadIdx.x;
  int Rm, Rn; bool diag;
  decode_tile((int)blockIdx.x, Rm, Rn, diag);
  const int bm = Rm >> 7, bn = Rn >> 7;

  f32x4 acc[4][4];
  gemm_tile(acc, lds, Xh, Rm, Rn, t);

  const int l  = t & 63;
  const int w  = t >> 6;
  const int wm = w >> 1, wn = w & 1;
  const int lc = l & 15, lq = l >> 4;

  int labr[4][4];
  #pragma unroll
  for (int fm = 0; fm < 4; ++fm)
    #pragma unroll
    for (int v = 0; v < 4; ++v)
      labr[fm][v] = labels[Rm + wm * 64 + fm * 16 + lq * 4 + v];

  float* sSNs = (float*)lds;          // [wn][wm][c64] std
  float* sSPs = sSNs + 256;
  float* sSNt = sSNs + 512;           // [wm][wn][r64] transposed
  float* sSPt = sSNs + 768;

  // std: stats for cols of Rn-block, reduced over this wave's 64 rows
  #pragma unroll
  for (int fn = 0; fn < 4; ++fn){
    const int gc = Rn + wn * 64 + fn * 16 + lc;
    const int labc = labels[gc];
    const float pb = pos_bound[gc];
    const float nb = neg_bound[gc];
    float sN = 0.f, sP = 0.f;
    #pragma unroll
    for (int fm = 0; fm < 4; ++fm)
      #pragma unroll
      for (int v = 0; v < 4; ++v){
        const float s = acc[fm][fn][v];
        const bool same = (labc == labr[fm][v]);
        sN += ((!same) && (s + 0.1f > pb)) ? __expf(40.0f * (s - 0.5f)) : 0.0f;
        sP += (same && (s - 0.1f < nb))    ? __expf(-2.0f * (s - 0.5f)) : 0.0f;
      }
    #pragma unroll
    for (int off = 16; off < 64; off <<= 1){
      sN += __shfl_xor(sN, off);
      sP += __shfl_xor(sP, off);
    }
    if (l < 16){
      const int c64 = fn * 16 + lc;
      sSNs[(wn * 2 + wm) * 64 + c64] = sN;
      sSPs[(wn * 2 + wm) * 64 + c64] = sP;
    }
  }
  // transposed: stats for cols == this tile's row indices (off-diag only)
  if (!diag){
    #pragma unroll
    for (int fm = 0; fm < 4; ++fm){
      float pbr[4], nbr[4];
      #pragma unroll
      for (int v = 0; v < 4; ++v){
        const int grow = Rm + wm * 64 + fm * 16 + lq * 4 + v;
        pbr[v] = pos_bound[grow];
        nbr[v] = neg_bound[grow];
      }
      float sN[4] = {0.f, 0.f, 0.f, 0.f}, sP[4] = {0.f, 0.f, 0.f, 0.f};
      #pragma unroll
      for (int fn = 0; fn < 4; ++fn){
        const int gc = Rn + wn * 64 + fn * 16 + lc;
        const int labc = labels[gc];
        #pragma unroll
        for (int v = 0; v < 4; ++v){
          const float s = acc[fm][fn][v];
          const bool same = (labc == labr[fm][v]);
          sN[v] += ((!same) && (s + 0.1f > pbr[v])) ? __expf(40.0f * (s - 0.5f)) : 0.0f;
          sP[v] += (same && (s - 0.1f < nbr[v]))    ? __expf(-2.0f * (s - 0.5f)) : 0.0f;
        }
      }
      #pragma unroll
      for (int off = 1; off < 16; off <<= 1)
        #pragma unroll
        for (int v = 0; v < 4; ++v){
          sN[v] += __shfl_xor(sN[v], off);
          sP[v] += __shfl_xor(sP[v], off);
        }
      if (lc == 0){
        #pragma unroll
        for (int v = 0; v < 4; ++v){
          const int r64 = fm * 16 + lq * 4 + v;
          sSNt[(wm * 2 + wn) * 64 + r64] = sN[v];
          sSPt[(wm * 2 + wn) * 64 + r64] = sP[v];
        }
      }
    }
  }
  __syncthreads();
  if (t < 128){
    const int h = t >> 6, r = t & 63;
    SNp[(size_t)bm * BS + Rn + t] = sSNs[(h * 2 + 0) * 64 + r] + sSNs[(h * 2 + 1) * 64 + r];
    SPp[(size_t)bm * BS + Rn + t] = sSPs[(h * 2 + 0) * 64 + r] + sSPs[(h * 2 + 1) * 64 + r];
    if (!diag){
      SNp[(size_t)bn * BS + Rm + t] = sSNt[(h * 2 + 0) * 64 + r] + sSNt[(h * 2 + 1) * 64 + r];
      SPp[(size_t)bn * BS + Rm + t] = sSPt[(h * 2 + 0) * 64 + r] + sSPt[(h * 2 + 1) * 64 + r];
    }
  }
}

// ---- K4: reduce stat partials + scalar loss (single block) ---------------
__global__ void k_finalize(const float* __restrict__ SNp, const float* __restrict__ SPp,
                           float* __restrict__ out)
{
  const int t = threadIdx.x;                  // 0..1023
  float sumP = 0.f, cP = 0.f, sumN = 0.f, cN = 0.f;
  #pragma unroll
  for (int i = 0; i < 4; ++i){
    const int c = t + i * 1024;
    float sn = 0.f, sp = 0.f;
    #pragma unroll
    for (int s = 0; s < NSLOT; ++s){
      sn += SNp[(size_t)s * BS + c];
      sp += SPp[(size_t)s * BS + c];
    }
    if (sn != 0.0f){ sumN += log1pf(sn); cN += 1.0f; }   // softplus(log S)=log1p(S)
    if (sp != 0.0f){ sumP += log1pf(sp); cP += 1.0f; }   // nz == (S != 0)
  }
  #pragma unroll
  for (int off = 32; off; off >>= 1){
    sumP += __shfl_down(sumP, off); cP += __shfl_down(cP, off);
    sumN += __shfl_down(sumN, off); cN += __shfl_down(cN, off);
  }
  __shared__ float red[16][4];
  const int w = t >> 6;
  if ((t & 63) == 0){ red[w][0] = sumP; red[w][1] = cP; red[w][2] = sumN; red[w][3] = cN; }
  __syncthreads();
  if (t == 0){
    float SPs = 0.f, CPs = 0.f, SNs = 0.f, CNs = 0.f;
    for (int i = 0; i < 16; ++i){ SPs += red[i][0]; CPs += red[i][1]; SNs += red[i][2]; CNs += red[i][3]; }
    const float LN2 = 0.69314718055994531f;   // softplus(0)
    const float tP = (CPs > 0.f) ? (SPs / 2.0f)  / fmaxf(CPs, 1.f) : LN2 / 2.0f;
    const float tN = (CNs > 0.f) ? (SNs / 40.0f) / fmaxf(CNs, 1.f) : LN2 / 40.0f;
    out[0] = tP + tN;
  }
}

// ---- launch --------------------------------------------------------------
extern "C" void kernel_launch(void* const* d_in, const int* in_sizes, int n_in,
                              void* d_out, int out_size, void* d_ws, size_t ws_size,
                              hipStream_t stream) {
  const float* x    = (const float*)d_in[0];   // batch (4096x512 fp32)
  const int* labels = (const int*)d_in[1];     // int32 labels
  char* W = (char*)d_ws;
  // ws (5 MB + 32 KB, all written-before-read, no memsets):
  //   Xh 4MB | P1 512KB (posB -> SNp) | P2 512KB (negB -> SPp)
  //   | pos_bound 16KB | neg_bound 16KB
  ushort* Xh        = (ushort*)W;
  float*  P1        = (float*)(W + (4u << 20));
  float*  P2        = (float*)(W + (4u << 20) + (512u << 10));
  float*  pos_bound = (float*)(W + (5u << 20));
  float*  neg_bound = (float*)(W + (5u << 20) + (16u << 10));

  k_convert<<<(BS * DIM / 4) / 256, 256, 0, stream>>>(x, Xh);
  k_bounds<<<NTILES, 256, 0, stream>>>(Xh, labels, P1, P2);
  k_redbounds<<<BS / 256, 256, 0, stream>>>(P1, P2, pos_bound, neg_bound);
  k_stats<<<NTILES, 256, 0, stream>>>(Xh, labels, pos_bound, neg_bound, P1, P2);
  k_finalize<<<1, 1024, 0, stream>>>(P1, P2, (float*)d_out);
}

// Round 10
// 151.593 us; speedup vs baseline: 1.2245x; 1.1837x over previous
//
#include <hip/hip_runtime.h>
#include <stdint.h>

// R10. Post-mortem of R9 (179.4us, absmax 0.0): atomic fix worked (WRITE_SIZE
// 165MB -> 1MB) but kernels are LATENCY-bound: k_stats 55.6us @ MfmaUtil 5.6%,
// VALUBusy 17%, Occupancy 7% (grid 528 -> ~2 blocks/CU, serialized
// load->drain->compute K-loop). k_bounds ~50-55 (same structure, absent from
// top5), k_finalize ~50 (single block reading 1MB). Two fixes:
//  1. 2-phase double-buffered K-loop (guide T3 minimal recipe, m248v2):
//     STAGE(next) overlaps compute(cur); asm vmcnt(0) + RAW s_barrier per step
//     (NOT __syncthreads, whose vmcnt(0)-drain before s_barrier would kill the
//     prefetch overlap). LDS 32->64KB, still 2 blocks/CU. Safety: every
//     ds_read is consumed by MFMA before the iteration barrier (lgkm drained),
//     sched_barrier(0) pins scheduling; STAGE at iter k overwrites the buffer
//     last read at iter k-1, protected by iter k-1's end barrier.
//  2. finalize split: k_redstats (16 blocks, coalesced) + k_final2 (1 wave).
// Unchanged validated pieces: bf16 sim, 528 upper-tri 128x128 tiles + dual
// epilogues, write-once partials (no atomics/memsets), nz == (S != 0),
// unshifted LSE (softplus(log S) = log1p(S)).

#define BS 4096
#define DIM 512
#define NTILES 528
#define NSLOT 32

typedef __attribute__((ext_vector_type(8))) short short8;
typedef __attribute__((ext_vector_type(4))) float f32x4;

#define TILE_USH (128 * 64)   // ushorts per LDS operand tile (16 KB)

#define VMW0 asm volatile("s_waitcnt vmcnt(0)" ::: "memory")

// ---- helpers -------------------------------------------------------------
__device__ __forceinline__ ushort f2bf(float f){             // RNE fp32->bf16
  unsigned u = __float_as_uint(f);
  return (ushort)((u + 0x7fffu + ((u >> 16) & 1u)) >> 16);
}
__device__ __forceinline__ void gld_lds16(void* ldsp, const void* gp){
  __builtin_amdgcn_global_load_lds((const __attribute__((address_space(1))) void*)gp,
                                   (__attribute__((address_space(3))) void*)ldsp, 16, 0, 0);
}

// ---- K0: fp32 -> bf16 ----------------------------------------------------
__global__ void k_convert(const float* __restrict__ x, ushort* __restrict__ xh){
  int i = blockIdx.x * blockDim.x + threadIdx.x;   // over BS*DIM/4
  float4 v = ((const float4*)x)[i];
  ((ushort4*)xh)[i] = make_ushort4(f2bf(v.x), f2bf(v.y), f2bf(v.z), f2bf(v.w));
}

// ---- tile decode: 528 upper-tri tiles, XCD-swizzled (528 = 8*66) ---------
__device__ __forceinline__ void decode_tile(int bid, int& Rm, int& Rn, bool& diag){
  int wg = (bid & 7) * 66 + (bid >> 3);
  int ii = wg, bm = 0;
  while (ii >= 32 - bm){ ii -= 32 - bm; ++bm; }
  const int bn = bm + ii;
  diag = (bm == bn);
  Rm = bm * 128; Rn = bn * 128;
}

// ---- staging: one K-step (64 cols) of A and B panels into one buffer -----
__device__ __forceinline__ void stage_ks(ushort* dstA, ushort* dstB,
                                         const ushort* __restrict__ Xh,
                                         int Rm, int Rn, int ks,
                                         int r0, int gx, int lds_i){
  const int kb = ks * 64 + gx * 8;
  #pragma unroll
  for (int rep = 0; rep < 4; ++rep){
    const int row = rep * 32 + r0;
    const int lo  = rep * 2048 + lds_i;
    gld_lds16(dstA + lo, Xh + (size_t)(Rm + row) * DIM + kb);
    gld_lds16(dstB + lo, Xh + (size_t)(Rn + row) * DIM + kb);
  }
}

// ---- GEMM core: 2-phase double-buffered (T3 minimal recipe) --------------
__device__ __forceinline__ void gemm_tile_db(f32x4 (&acc)[4][4],
                                             ushort (&lds)[2][2 * TILE_USH],
                                             const ushort* __restrict__ Xh,
                                             int Rm, int Rn, int t)
{
  const int l  = t & 63;
  const int w  = t >> 6;
  const int wm = w >> 1, wn = w & 1;
  const int lc = l & 15;
  const int lq = l >> 4;
  const int r0 = t >> 3;
  const int gx = (t & 7) ^ (r0 & 7);          // XOR-swizzled source col-group
  const int lds_i = t * 8;

  #pragma unroll
  for (int i = 0; i < 4; ++i)
    #pragma unroll
    for (int j = 0; j < 4; ++j) acc[i][j] = (f32x4){0.f, 0.f, 0.f, 0.f};

  // prologue: stage ks=0 into buf0, wait, barrier
  stage_ks(&lds[0][0], &lds[0][TILE_USH], Xh, Rm, Rn, 0, r0, gx, lds_i);
  VMW0;
  __builtin_amdgcn_s_barrier();
  __builtin_amdgcn_sched_barrier(0);

  #pragma unroll
  for (int ks = 0; ks < 8; ++ks){
    const int cur = ks & 1;
    if (ks < 7)
      stage_ks(&lds[cur ^ 1][0], &lds[cur ^ 1][TILE_USH], Xh, Rm, Rn, ks + 1, r0, gx, lds_i);
    // compute current buffer (every ds_read consumed by MFMA -> lgkm drained
    // before the end-of-iter barrier)
    #pragma unroll
    for (int kk = 0; kk < 2; ++kk){
      const int gr = kk * 4 + lq;
      const int sl = (gr ^ (l & 7)) * 8;
      short8 ah[4], bh[4];
      #pragma unroll
      for (int f = 0; f < 4; ++f){
        ah[f] = *(const short8*)&lds[cur][(wm * 64 + f * 16 + lc) * 64 + sl];
        bh[f] = *(const short8*)&lds[cur][TILE_USH + (wn * 64 + f * 16 + lc) * 64 + sl];
      }
      #pragma unroll
      for (int fm = 0; fm < 4; ++fm)
        #pragma unroll
        for (int fn = 0; fn < 4; ++fn)
          acc[fm][fn] = __builtin_amdgcn_mfma_f32_16x16x32_bf16(ah[fm], bh[fn], acc[fm][fn], 0, 0, 0);
    }
    __builtin_amdgcn_sched_barrier(0);
    VMW0;                              // next buffer's loads complete
    __builtin_amdgcn_s_barrier();      // + all waves done reading cur buffer
    __builtin_amdgcn_sched_barrier(0);
  }
}

// ---- K1: GEMM + per-row bound PARTIALS -----------------------------------
// posB/negB float[NSLOT][BS]; for row-tile r: slot s>=r by std of tile (r,s)
// (diag incl.), slot s<r by transposed of tile (s,r). Each written once.
__global__ __launch_bounds__(256)
void k_bounds(const ushort* __restrict__ Xh, const int* __restrict__ labels,
              float* __restrict__ posB, float* __restrict__ negB)
{
  __shared__ ushort lds[2][2 * TILE_USH];
  const int t = threadIdx.x;
  int Rm, Rn; bool diag;
  decode_tile((int)blockIdx.x, Rm, Rn, diag);
  const int bm = Rm >> 7, bn = Rn >> 7;

  f32x4 acc[4][4];
  gemm_tile_db(acc, lds, Xh, Rm, Rn, t);

  const int l  = t & 63;
  const int w  = t >> 6;
  const int wm = w >> 1, wn = w & 1;
  const int lc = l & 15, lq = l >> 4;
  const float INF = __builtin_inff();

  int labr[4][4];
  #pragma unroll
  for (int fm = 0; fm < 4; ++fm)
    #pragma unroll
    for (int v = 0; v < 4; ++v)
      labr[fm][v] = labels[Rm + wm * 64 + fm * 16 + lq * 4 + v];

  // LDS scratch aliases GEMM buffer 0 (dead after K-loop); full sync first
  __syncthreads();
  float* sMnS = (float*)&lds[0][0];   // [wm][wn][r64] std per-row min
  float* sMxS = sMnS + 256;           // std per-row max
  float* sMnT = sMnS + 512;           // [wn][wm][c64] transposed min
  float* sMxT = sMnS + 768;           // transposed max

  // std: bounds for rows of Rm-block over this wave's 64 cols
  #pragma unroll
  for (int fm = 0; fm < 4; ++fm){
    float mn[4] = {INF, INF, INF, INF};
    float mx[4] = {-INF, -INF, -INF, -INF};
    #pragma unroll
    for (int fn = 0; fn < 4; ++fn){
      const int gc = Rn + wn * 64 + fn * 16 + lc;
      const int labc = labels[gc];
      #pragma unroll
      for (int v = 0; v < 4; ++v){
        const float s = acc[fm][fn][v];
        const int grow = Rm + wm * 64 + fm * 16 + lq * 4 + v;
        const bool same = (labc == labr[fm][v]);
        mn[v] = fminf(mn[v], (same && (grow != gc)) ? s : INF);
        mx[v] = fmaxf(mx[v], same ? -INF : s);
      }
    }
    #pragma unroll
    for (int off = 1; off < 16; off <<= 1)
      #pragma unroll
      for (int v = 0; v < 4; ++v){
        mn[v] = fminf(mn[v], __shfl_xor(mn[v], off));
        mx[v] = fmaxf(mx[v], __shfl_xor(mx[v], off));
      }
    if (lc == 0){
      #pragma unroll
      for (int v = 0; v < 4; ++v){
        const int r64 = fm * 16 + lq * 4 + v;
        sMnS[(wm * 2 + wn) * 64 + r64] = mn[v];
        sMxS[(wm * 2 + wn) * 64 + r64] = mx[v];
      }
    }
  }
  if (!diag){
    // transposed: bounds for rows == this tile's column indices
    #pragma unroll
    for (int fn = 0; fn < 4; ++fn){
      const int gc = Rn + wn * 64 + fn * 16 + lc;
      const int labc = labels[gc];
      float mn = INF, mx = -INF;
      #pragma unroll
      for (int fm = 0; fm < 4; ++fm)
        #pragma unroll
        for (int v = 0; v < 4; ++v){
          const float s = acc[fm][fn][v];
          const bool same = (labc == labr[fm][v]);
          mn = fminf(mn, same ? s : INF);        // grow != gc off-diagonal
          mx = fmaxf(mx, same ? -INF : s);
        }
      #pragma unroll
      for (int off = 16; off < 64; off <<= 1){
        mn = fminf(mn, __shfl_xor(mn, off));
        mx = fmaxf(mx, __shfl_xor(mx, off));
      }
      if (l < 16){
        const int c64 = fn * 16 + lc;
        sMnT[(wn * 2 + wm) * 64 + c64] = mn;
        sMxT[(wn * 2 + wm) * 64 + c64] = mx;
      }
    }
  }
  __syncthreads();
  if (t < 128){
    const int h = t >> 6, r = t & 63;
    posB[(size_t)bn * BS + Rm + t] = fminf(sMnS[(h * 2 + 0) * 64 + r], sMnS[(h * 2 + 1) * 64 + r]);
    negB[(size_t)bn * BS + Rm + t] = fmaxf(sMxS[(h * 2 + 0) * 64 + r], sMxS[(h * 2 + 1) * 64 + r]);
    if (!diag){
      posB[(size_t)bm * BS + Rn + t] = fminf(sMnT[(h * 2 + 0) * 64 + r], sMnT[(h * 2 + 1) * 64 + r]);
      negB[(size_t)bm * BS + Rn + t] = fmaxf(sMxT[(h * 2 + 0) * 64 + r], sMxT[(h * 2 + 1) * 64 + r]);
    }
  }
}

// ---- K2: reduce bound partials 32 -> 1 -----------------------------------
__global__ void k_redbounds(const float* __restrict__ posB, const float* __restrict__ negB,
                            float* __restrict__ pos_bound, float* __restrict__ neg_bound){
  const int r = blockIdx.x * 256 + threadIdx.x;   // 16 blocks x 256
  float mn = __builtin_inff(), mx = -__builtin_inff();
  #pragma unroll
  for (int s = 0; s < NSLOT; ++s){
    mn = fminf(mn, posB[(size_t)s * BS + r]);
    mx = fmaxf(mx, negB[(size_t)s * BS + r]);
  }
  pos_bound[r] = mn;            // empty class -> +inf (masks all-false, as ref)
  neg_bound[r] = mx;            // empty -> -inf
}

// ---- K3: GEMM + per-col sum-exp PARTIALS ---------------------------------
// SNp/SPp float[NSLOT][BS]; for col-tile c: slot s<=c by std of tile (s,c)
// (diag incl.), slot s>c by transposed of tile (c,s). Each written once.
__global__ __launch_bounds__(256)
void k_stats(const ushort* __restrict__ Xh, const int* __restrict__ labels,
             const float* __restrict__ pos_bound, const float* __restrict__ neg_bound,
             float* __restrict__ SNp, float* __restrict__ SPp)
{
  __shared__ ushort lds[2][2 * TILE_USH];
  const int t = threadIdx.x;
  int Rm, Rn; bool diag;
  decode_tile((int)blockIdx.x, Rm, Rn, diag);
  const int bm = Rm >> 7, bn = Rn >> 7;

  f32x4 acc[4][4];
  gemm_tile_db(acc, lds, Xh, Rm, Rn, t);

  const int l  = t & 63;
  const int w  = t >> 6;
  const int wm = w >> 1, wn = w & 1;
  const int lc = l & 15, lq = l >> 4;

  int labr[4][4];
  #pragma unroll
  for (int fm = 0; fm < 4; ++fm)
    #pragma unroll
    for (int v = 0; v < 4; ++v)
      labr[fm][v] = labels[Rm + wm * 64 + fm * 16 + lq * 4 + v];

  __syncthreads();
  float* sSNs = (float*)&lds[0][0];   // [wn][wm][c64] std
  float* sSPs = sSNs + 256;
  float* sSNt = sSNs + 512;           // [wm][wn][r64] transposed
  float* sSPt = sSNs + 768;

  // std: stats for cols of Rn-block, reduced over this wave's 64 rows
  #pragma unroll
  for (int fn = 0; fn < 4; ++fn){
    const int gc = Rn + wn * 64 + fn * 16 + lc;
    const int labc = labels[gc];
    const float pb = pos_bound[gc];
    const float nb = neg_bound[gc];
    float sN = 0.f, sP = 0.f;
    #pragma unroll
    for (int fm = 0; fm < 4; ++fm)
      #pragma unroll
      for (int v = 0; v < 4; ++v){
        const float s = acc[fm][fn][v];
        const bool same = (labc == labr[fm][v]);
        sN += ((!same) && (s + 0.1f > pb)) ? __expf(40.0f * (s - 0.5f)) : 0.0f;
        sP += (same && (s - 0.1f < nb))    ? __expf(-2.0f * (s - 0.5f)) : 0.0f;
      }
    #pragma unroll
    for (int off = 16; off < 64; off <<= 1){
      sN += __shfl_xor(sN, off);
      sP += __shfl_xor(sP, off);
    }
    if (l < 16){
      const int c64 = fn * 16 + lc;
      sSNs[(wn * 2 + wm) * 64 + c64] = sN;
      sSPs[(wn * 2 + wm) * 64 + c64] = sP;
    }
  }
  if (!diag){
    // transposed: stats for cols == this tile's row indices
    #pragma unroll
    for (int fm = 0; fm < 4; ++fm){
      float pbr[4], nbr[4];
      #pragma unroll
      for (int v = 0; v < 4; ++v){
        const int grow = Rm + wm * 64 + fm * 16 + lq * 4 + v;
        pbr[v] = pos_bound[grow];
        nbr[v] = neg_bound[grow];
      }
      float sN[4] = {0.f, 0.f, 0.f, 0.f}, sP[4] = {0.f, 0.f, 0.f, 0.f};
      #pragma unroll
      for (int fn = 0; fn < 4; ++fn){
        const int gc = Rn + wn * 64 + fn * 16 + lc;
        const int labc = labels[gc];
        #pragma unroll
        for (int v = 0; v < 4; ++v){
          const float s = acc[fm][fn][v];
          const bool same = (labc == labr[fm][v]);
          sN[v] += ((!same) && (s + 0.1f > pbr[v])) ? __expf(40.0f * (s - 0.5f)) : 0.0f;
          sP[v] += (same && (s - 0.1f < nbr[v]))    ? __expf(-2.0f * (s - 0.5f)) : 0.0f;
        }
      }
      #pragma unroll
      for (int off = 1; off < 16; off <<= 1)
        #pragma unroll
        for (int v = 0; v < 4; ++v){
          sN[v] += __shfl_xor(sN[v], off);
          sP[v] += __shfl_xor(sP[v], off);
        }
      if (lc == 0){
        #pragma unroll
        for (int v = 0; v < 4; ++v){
          const int r64 = fm * 16 + lq * 4 + v;
          sSNt[(wm * 2 + wn) * 64 + r64] = sN[v];
          sSPt[(wm * 2 + wn) * 64 + r64] = sP[v];
        }
      }
    }
  }
  __syncthreads();
  if (t < 128){
    const int h = t >> 6, r = t & 63;
    SNp[(size_t)bm * BS + Rn + t] = sSNs[(h * 2 + 0) * 64 + r] + sSNs[(h * 2 + 1) * 64 + r];
    SPp[(size_t)bm * BS + Rn + t] = sSPs[(h * 2 + 0) * 64 + r] + sSPs[(h * 2 + 1) * 64 + r];
    if (!diag){
      SNp[(size_t)bn * BS + Rm + t] = sSNt[(h * 2 + 0) * 64 + r] + sSNt[(h * 2 + 1) * 64 + r];
      SPp[(size_t)bn * BS + Rm + t] = sSPt[(h * 2 + 0) * 64 + r] + sSPt[(h * 2 + 1) * 64 + r];
    }
  }
}

// ---- K4a: reduce stat partials, 16 blocks -> 16 float4 -------------------
__global__ void k_redstats(const float* __restrict__ SNp, const float* __restrict__ SPp,
                           float4* __restrict__ part)
{
  const int t = threadIdx.x;
  const int c = blockIdx.x * 256 + t;             // 16 blocks x 256
  float sn = 0.f, sp = 0.f;
  #pragma unroll
  for (int s = 0; s < NSLOT; ++s){
    sn += SNp[(size_t)s * BS + c];
    sp += SPp[(size_t)s * BS + c];
  }
  float sumP = (sp != 0.f) ? log1pf(sp) : 0.f;    // softplus(log S) = log1p(S)
  float cP   = (sp != 0.f) ? 1.f : 0.f;           // nz == (S != 0)
  float sumN = (sn != 0.f) ? log1pf(sn) : 0.f;
  float cN   = (sn != 0.f) ? 1.f : 0.f;
  #pragma unroll
  for (int off = 32; off; off >>= 1){
    sumP += __shfl_down(sumP, off); cP += __shfl_down(cP, off);
    sumN += __shfl_down(sumN, off); cN += __shfl_down(cN, off);
  }
  __shared__ float red[4][4];
  const int w = t >> 6;
  if ((t & 63) == 0){ red[w][0] = sumP; red[w][1] = cP; red[w][2] = sumN; red[w][3] = cN; }
  __syncthreads();
  if (t == 0){
    float a = 0.f, b = 0.f, c2 = 0.f, d = 0.f;
    for (int i = 0; i < 4; ++i){ a += red[i][0]; b += red[i][1]; c2 += red[i][2]; d += red[i][3]; }
    part[blockIdx.x] = make_float4(a, b, c2, d);
  }
}

// ---- K4b: final scalar (single wave) -------------------------------------
__global__ void k_final2(const float4* __restrict__ part, float* __restrict__ out)
{
  const int l = threadIdx.x;                      // 64 threads
  float4 v = (l < 16) ? part[l] : make_float4(0.f, 0.f, 0.f, 0.f);
  float sumP = v.x, cP = v.y, sumN = v.z, cN = v.w;
  #pragma unroll
  for (int off = 8; off; off >>= 1){
    sumP += __shfl_down(sumP, off); cP += __shfl_down(cP, off);
    sumN += __shfl_down(sumN, off); cN += __shfl_down(cN, off);
  }
  if (l == 0){
    const float LN2 = 0.69314718055994531f;       // softplus(0)
    const float tP = (cP > 0.f) ? (sumP / 2.0f)  / fmaxf(cP, 1.f) : LN2 / 2.0f;
    const float tN = (cN > 0.f) ? (sumN / 40.0f) / fmaxf(cN, 1.f) : LN2 / 40.0f;
    out[0] = tP + tN;
  }
}

// ---- launch --------------------------------------------------------------
extern "C" void kernel_launch(void* const* d_in, const int* in_sizes, int n_in,
                              void* d_out, int out_size, void* d_ws, size_t ws_size,
                              hipStream_t stream) {
  const float* x    = (const float*)d_in[0];   // batch (4096x512 fp32)
  const int* labels = (const int*)d_in[1];     // int32 labels
  char* W = (char*)d_ws;
  // ws (~5.03 MB, all written-before-read, no memsets):
  //   Xh 4MB | P1 512KB (posB -> SNp) | P2 512KB (negB -> SPp)
  //   | pos_bound 16KB | neg_bound 16KB | part 256B
  ushort* Xh        = (ushort*)W;
  float*  P1        = (float*)(W + (4u << 20));
  float*  P2        = (float*)(W + (4u << 20) + (512u << 10));
  float*  pos_bound = (float*)(W + (5u << 20));
  float*  neg_bound = (float*)(W + (5u << 20) + (16u << 10));
  float4* part      = (float4*)(W + (5u << 20) + (32u << 10));

  k_convert<<<(BS * DIM / 4) / 256, 256, 0, stream>>>(x, Xh);
  k_bounds<<<NTILES, 256, 0, stream>>>(Xh, labels, P1, P2);
  k_redbounds<<<BS / 256, 256, 0, stream>>>(P1, P2, pos_bound, neg_bound);
  k_stats<<<NTILES, 256, 0, stream>>>(Xh, labels, pos_bound, neg_bound, P1, P2);
  k_redstats<<<BS / 256, 256, 0, stream>>>(P1, P2, part);
  k_final2<<<1, 64, 0, stream>>>(part, (float*)d_out);
}